// Round 11
// baseline (24.928 us; speedup 1.0000x reference)
//
#include <hip/hip_runtime.h>
#include <float.h>

// Chamfer distance, B=16, N=2048, D=3, fp32 — memset + ONE kernel.
// cd[b] = mean_j min_i |x_i - y_j|^2 + mean_i min_j |x_i - y_j|^2
// Pair form: |q - r|^2 = 2*(0.5|r|^2 - q.r) + |q|^2.
// Block (512 thr, 8 waves) stages ALL 2048 refs of (b,dir) in 32 KB LDS
// (SoA + halfnorm). Wave = ref-eighth (wave-uniform -> broadcast
// ds_read_b128, conflict-free), lane = 4 queries -> 4 reads serve
// 4 refs x 4 queries (4x fewer DS instr than lane-per-query). Cross-wave
// min via LDS, wave-0 applies 2m+|q|^2, block-sums, atomicAdd into out[b]
// (all-positive adds; reorder error ~1e-6 << 2.3e-3 threshold).
// Inner loop: scalar v_fma_f32 (full-rate; packed is half-rate on gfx950)
// + v_min3_f32 = 3.5 instr/pair.

constexpr int B_ = 16;
constexpr int N_ = 2048;
constexpr int THREADS = 512;
constexpr int WAVES = THREADS / 64;       // 8 ref-slices
constexpr int QPT = 4;                    // queries per lane
constexpr int QBLK = 64 * QPT;            // 256 queries per block
constexpr int QS = N_ / QBLK;             // 8 query slices
constexpr int GRP_PER_WAVE = (N_ / WAVES) / 4;  // 64 groups of 4 refs
constexpr int PPT = N_ / THREADS;         // 4 ref points staged per thread

typedef float v4f __attribute__((ext_vector_type(4)));

__global__ __launch_bounds__(THREADS)
void cd_min_kernel(const float* __restrict__ x,
                   const float* __restrict__ y,
                   float* __restrict__ out) {
    const int qs  = blockIdx.x;           // 0..7
    const int b   = blockIdx.y;           // 0..15
    const int dir = blockIdx.z;           // 0..1
    const int t   = (int)threadIdx.x;
    const int w   = t >> 6;               // wave id = ref slice
    const int l   = t & 63;               // lane

    const float* __restrict__ q = dir ? y : x;
    const float* __restrict__ r = dir ? x : y;

    // ---- stage ALL refs for (b,dir): SoA rows + halfnorm (32 KB) ----
    __shared__ __align__(16) float lref[4][N_];
    {
        const int p0 = t * PPT;           // 4 points = 48 B contiguous
        const float4* rv = (const float4*)(r + ((size_t)b * N_ + p0) * 3);
        float buf[3 * PPT];
        #pragma unroll
        for (int v = 0; v < 3; ++v) {
            const float4 tv = rv[v];
            buf[4 * v + 0] = tv.x; buf[4 * v + 1] = tv.y;
            buf[4 * v + 2] = tv.z; buf[4 * v + 3] = tv.w;
        }
        #pragma unroll
        for (int k = 0; k < PPT; ++k) {
            const float rx = buf[3 * k + 0];
            const float ry = buf[3 * k + 1];
            const float rz = buf[3 * k + 2];
            lref[0][p0 + k] = rx;
            lref[1][p0 + k] = ry;
            lref[2][p0 + k] = rz;
            lref[3][p0 + k] = 0.5f * (rx * rx + ry * ry + rz * rz);
        }
    }

    // ---- this lane's 4 queries (same for every wave) ----
    const int q0 = qs * QBLK + l * QPT;   // 4 queries = 48 B contiguous
    float qnx[QPT], qny[QPT], qnz[QPT], q2[QPT], best[QPT];
    {
        const float4* qv = (const float4*)(q + ((size_t)b * N_ + q0) * 3);
        float qf[3 * QPT];
        #pragma unroll
        for (int v = 0; v < 3; ++v) {
            const float4 tv = qv[v];
            qf[4 * v + 0] = tv.x; qf[4 * v + 1] = tv.y;
            qf[4 * v + 2] = tv.z; qf[4 * v + 3] = tv.w;
        }
        #pragma unroll
        for (int k = 0; k < QPT; ++k) {
            const float a0 = qf[3 * k + 0];
            const float a1 = qf[3 * k + 1];
            const float a2 = qf[3 * k + 2];
            qnx[k] = -a0; qny[k] = -a1; qnz[k] = -a2;
            q2[k]  = a0 * a0 + a1 * a1 + a2 * a2;
            best[k] = FLT_MAX;
        }
    }
    __syncthreads();

    // ---- min over this wave's 256 refs (64 groups, broadcast reads) ----
    const v4f* __restrict__ lx = (const v4f*)lref[0];
    const v4f* __restrict__ ly = (const v4f*)lref[1];
    const v4f* __restrict__ lz = (const v4f*)lref[2];
    const v4f* __restrict__ lh = (const v4f*)lref[3];

    const int g0 = w * GRP_PER_WAVE;
    #pragma unroll 4
    for (int g = g0; g < g0 + GRP_PER_WAVE; ++g) {
        const v4f X = lx[g], Y = ly[g], Z = lz[g], H = lh[g];
        #pragma unroll
        for (int k = 0; k < QPT; ++k) {
            float a0 = fmaf(qnx[k], X.x, H.x);
            a0 = fmaf(qny[k], Y.x, a0);
            a0 = fmaf(qnz[k], Z.x, a0);
            float a1 = fmaf(qnx[k], X.y, H.y);
            a1 = fmaf(qny[k], Y.y, a1);
            a1 = fmaf(qnz[k], Z.y, a1);
            float a2 = fmaf(qnx[k], X.z, H.z);
            a2 = fmaf(qny[k], Y.z, a2);
            a2 = fmaf(qnz[k], Z.z, a2);
            float a3 = fmaf(qnx[k], X.w, H.w);
            a3 = fmaf(qny[k], Y.w, a3);
            a3 = fmaf(qnz[k], Z.w, a3);
            best[k] = fminf(fminf(best[k], a0), a1);   // v_min3_f32
            best[k] = fminf(fminf(best[k], a2), a3);   // v_min3_f32
        }
    }

    // ---- cross-wave min (8 slices) ----
    __shared__ v4f cmin4[WAVES][64];      // 8 KB
    cmin4[w][l] = (v4f){best[0], best[1], best[2], best[3]};
    __syncthreads();

    // ---- wave 0: final per-query min, epilogue, block sum, atomic ----
    if (t < 64) {
        v4f m = cmin4[0][l];
        #pragma unroll
        for (int s = 1; s < WAVES; ++s)
            m = __builtin_elementwise_min(m, cmin4[s][l]);

        float sum = (fmaf(2.0f, m.x, q2[0]) + fmaf(2.0f, m.y, q2[1]))
                  + (fmaf(2.0f, m.z, q2[2]) + fmaf(2.0f, m.w, q2[3]));

        #pragma unroll
        for (int o = 32; o > 0; o >>= 1)
            sum += __shfl_down(sum, o, 64);

        if (l == 0)
            atomicAdd(&out[b], sum * (1.0f / (float)N_));
    }
}

extern "C" void kernel_launch(void* const* d_in, const int* in_sizes, int n_in,
                              void* d_out, int out_size, void* d_ws, size_t ws_size,
                              hipStream_t stream) {
    const float* x = (const float*)d_in[0];
    const float* y = (const float*)d_in[1];
    float* out     = (float*)d_out;

    hipMemsetAsync(out, 0, B_ * sizeof(float), stream);
    cd_min_kernel<<<dim3(QS, B_, 2), dim3(THREADS), 0, stream>>>(x, y, out);
}